// Round 1
// baseline (154.767 us; speedup 1.0000x reference)
//
#include <hip/hip_runtime.h>

#define HID   384
#define K_PE  768     // 3*16*16
#define IMGST 150528  // 3*224*224 floats per image
#define MSUB  16      // rows (images) per block after 4-way M-split

typedef unsigned short ushort_t;
using f32x4  = __attribute__((ext_vector_type(4))) float;
using short8 = __attribute__((ext_vector_type(8))) short;

// ---- bf16 helpers (RNE) ----------------------------------------------------
__device__ __forceinline__ unsigned bfpack(float lo, float hi) {
    union { float f; unsigned u; } a, b; a.f = lo; b.f = hi;
    unsigned ra = (a.u + 0x7fffu + ((a.u >> 16) & 1u)) >> 16;
    unsigned rb = (b.u + 0x7fffu + ((b.u >> 16) & 1u)) & 0xffff0000u;
    return ra | rb;
}

// ---------------- prep: zero scalars + swizzle W into B-frag order ----------
// Wfrag: [nt(24)][kc(24)][lane(64)][8] bf16; B-frag n = nt*16 + (lane&15),
// k = kc*32 + (lane>>4)*8 + j -> one frag load = one contiguous 1 KB segment.
// grid 144 x 256 = 36864 threads = 384 rows x 96 k-octets.
__global__ __launch_bounds__(256) void prep(const float* __restrict__ W,
                                            ushort_t* __restrict__ Wfrag,
                                            float* __restrict__ scal) {
    const int t = blockIdx.x * 256 + threadIdx.x;
    if (t < 4) scal[t] = 0.f;                  // T, S, pad, done-counter
    const int n  = t / 96;                     // 0..383
    const int ko = t % 96;                     // k-octet
    const float4 a = *(const float4*)(W + (size_t)n * K_PE + ko * 8);
    const float4 b = *(const float4*)(W + (size_t)n * K_PE + ko * 8 + 4);
    uint4 p;
    p.x = bfpack(a.x, a.y); p.y = bfpack(a.z, a.w);
    p.z = bfpack(b.x, b.y); p.w = bfpack(b.z, b.w);
    const int nt   = n >> 4;
    const int kc   = ko >> 2;
    const int lane = (ko & 3) * 16 + (n & 15);
    ((uint4*)Wfrag)[(nt * 24 + kc) * 64 + lane] = p;
}

// ---------------- fused GEMM + softmax kernel --------------------------------
// grid 784 = 196 positions x 4 image-quarters (M=16). block 256 = 4 waves.
// Each wave: all 16 rows x 96 cols (6 ni frags), acc = 48 VGPRs.
// 3 independent blocks co-resident per CU (launch_bounds 256,3) -> latency
// hiding across barrier domains. T14 staging: issue loads early, pack+write
// late (after the MFMAs), single barrier per K-step.
// Epilogue: fused softmax (fp32). T_p partial -> atomicAdd(scal[0]).
// Per-block column sums L[c], Q[c] -> private slots Lg/Qg[blk][c] (the S
// reduction couples all 64 images of a position -> finished in kernel 3).
__global__ __launch_bounds__(256, 3) void pe_all(
    const float* __restrict__ xin, const float* __restrict__ yin,
    const ushort_t* __restrict__ Wfrag, const float* __restrict__ bias,
    float* __restrict__ scal, float* __restrict__ Lg, float* __restrict__ Qg) {
    const int blk = blockIdx.x;        // 0..783
    const int p   = blk >> 2;          // patch position
    const int sub = blk & 3;           // image quarter
    const int pi  = p / 14;
    const int pj  = p - pi * 14;

    __shared__ __align__(16) ushort_t Asx[2][MSUB * 64];  // 2 x 2 KB
    __shared__ __align__(16) ushort_t Asy[2][MSUB * 64];  // 2 x 2 KB
    __shared__ float Smx[4][16], Ssx[4][16], Smy[4][16], Ssy[4][16];
    __shared__ float sT[4];

    const int tid  = threadIdx.x;
    const int wave = tid >> 6;        // 0..3 = n-wave (96 cols each)
    const int lane = tid & 63;
    const int lm   = lane & 15;
    const int lq   = lane >> 4;

    // ---- stage ids: one k-octet of one matrix per thread
    const int mat  = tid >> 7;        // 0:x  1:y
    const int sidx = tid & 127;
    const int srow = sidx & 15;       // image row within the quarter
    const int soct = sidx >> 4;       // k-octet 0..7
    const float* sbase = (mat ? yin : xin) +
        (size_t)(sub * MSUB + srow) * IMGST + pi * 3584 + pj * 16;
    ushort_t (* const Adst)[MSUB * 64] = mat ? Asy : Asx;
    const int woff = srow * 64 + ((soct ^ (srow & 7)) * 8);

    // ---- frag read offsets (k-step invariant)
    int ard[2];
#pragma unroll
    for (int ks = 0; ks < 2; ++ks)
        ard[ks] = lm * 64 + (((ks * 4 + lq) ^ (lm & 7)) * 8);

    const ushort_t* bbase = Wfrag + (size_t)lane * 8;

    f32x4 accx[6] = {};
    f32x4 accy[6] = {};

    // prologue: stage kbi=0 into buffer 0
    {
        const int k0  = soct * 8;
        const int off = (k0 >> 8) * 50176 + (((k0 >> 4) & 15) * 224) + (k0 & 15);
        const float4 f0 = *(const float4*)(sbase + off);
        const float4 f1 = *(const float4*)(sbase + off + 4);
        uint4 px;
        px.x = bfpack(f0.x, f0.y); px.y = bfpack(f0.z, f0.w);
        px.z = bfpack(f1.x, f1.y); px.w = bfpack(f1.z, f1.w);
        *(uint4*)&Adst[0][woff] = px;
    }
    __syncthreads();

    for (int kbi = 0; kbi < 12; ++kbi) {
        const int cur = kbi & 1;
        // T14: issue next-tile loads NOW (dummy re-load of octet 0 on last
        // iter keeps the loop branchless; its write lands in a dead buffer).
        const int kn  = (kbi < 11) ? (kbi + 1) * 64 + soct * 8 : soct * 8;
        const int off = (kn >> 8) * 50176 + (((kn >> 4) & 15) * 224) + (kn & 15);
        const float4 f0 = *(const float4*)(sbase + off);
        const float4 f1 = *(const float4*)(sbase + off + 4);

#pragma unroll
        for (int ks = 0; ks < 2; ++ks) {
            short8 bfr[6];
#pragma unroll
            for (int ni = 0; ni < 6; ++ni)
                bfr[ni] = *(const short8*)(bbase +
                          (size_t)(((wave * 6 + ni) * 24 + kbi * 2 + ks) * 64) * 8);
            const short8 afx = *(const short8*)&Asx[cur][ard[ks]];
            const short8 afy = *(const short8*)&Asy[cur][ard[ks]];
#pragma unroll
            for (int ni = 0; ni < 6; ++ni) {
                accx[ni] = __builtin_amdgcn_mfma_f32_16x16x32_bf16(
                    afx, bfr[ni], accx[ni], 0, 0, 0);
                accy[ni] = __builtin_amdgcn_mfma_f32_16x16x32_bf16(
                    afy, bfr[ni], accy[ni], 0, 0, 0);
            }
        }

        // write-late: vmcnt wait + pack + LDS store AFTER the MFMAs
        uint4 px;
        px.x = bfpack(f0.x, f0.y); px.y = bfpack(f0.z, f0.w);
        px.z = bfpack(f1.x, f1.y); px.w = bfpack(f1.z, f1.w);
        *(uint4*)&Adst[cur ^ 1][woff] = px;
        __syncthreads();
    }

    // ---- epilogue ----------------------------------------------------------
    // D frag: col = wave*96 + ni*16 + lm; row = lq*4 + r  (16 rows).
#pragma unroll
    for (int ni = 0; ni < 6; ++ni) {
        const float bv = bias[wave * 96 + ni * 16 + lm];
#pragma unroll
        for (int r = 0; r < 4; ++r) {
            accx[ni][r] += bv;
            accy[ni][r] += bv;
        }
    }

    // row max over this wave's 96 cols, butterfly within the 16-lane lm group
    float mx[4], my_[4];
#pragma unroll
    for (int r = 0; r < 4; ++r) {
        float a = accx[0][r], b = accy[0][r];
#pragma unroll
        for (int ni = 1; ni < 6; ++ni) {
            a = fmaxf(a, accx[ni][r]);
            b = fmaxf(b, accy[ni][r]);
        }
        mx[r] = a; my_[r] = b;
    }
#pragma unroll
    for (int off = 1; off < 16; off <<= 1)
#pragma unroll
        for (int r = 0; r < 4; ++r) {
            mx[r]  = fmaxf(mx[r],  __shfl_xor(mx[r],  off));
            my_[r] = fmaxf(my_[r], __shfl_xor(my_[r], off));
        }
    if (lm == 0)
#pragma unroll
        for (int r = 0; r < 4; ++r) {
            Smx[wave][lq * 4 + r] = mx[r];
            Smy[wave][lq * 4 + r] = my_[r];
        }
    __syncthreads();
#pragma unroll
    for (int r = 0; r < 4; ++r) {
        const int row = lq * 4 + r;
        mx[r]  = fmaxf(fmaxf(Smx[0][row], Smx[1][row]),
                       fmaxf(Smx[2][row], Smx[3][row]));
        my_[r] = fmaxf(fmaxf(Smy[0][row], Smy[1][row]),
                       fmaxf(Smy[2][row], Smy[3][row]));
    }

    // row sum of exp (x and y) against the full-row max
    float sx[4], sy[4];
#pragma unroll
    for (int r = 0; r < 4; ++r) {
        float a = 0.f, b = 0.f;
#pragma unroll
        for (int ni = 0; ni < 6; ++ni) {
            a += __expf(accx[ni][r] - mx[r]);
            b += __expf(accy[ni][r] - my_[r]);
        }
        sx[r] = a; sy[r] = b;
    }
#pragma unroll
    for (int off = 1; off < 16; off <<= 1)
#pragma unroll
        for (int r = 0; r < 4; ++r) {
            sx[r] += __shfl_xor(sx[r], off);
            sy[r] += __shfl_xor(sy[r], off);
        }
    if (lm == 0)
#pragma unroll
        for (int r = 0; r < 4; ++r) {
            Ssx[wave][lq * 4 + r] = sx[r];
            Ssy[wave][lq * 4 + r] = sy[r];
        }
    __syncthreads();
    float shx[4], invy[4];
#pragma unroll
    for (int r = 0; r < 4; ++r) {
        const int row = lq * 4 + r;
        const float ssx = Ssx[0][row] + Ssx[1][row] + Ssx[2][row] + Ssx[3][row];
        const float ssy = Ssy[0][row] + Ssy[1][row] + Ssy[2][row] + Ssy[3][row];
        shx[r]  = mx[r] + __logf(ssx);   // logp shift
        invy[r] = 1.f / ssy;             // q scale
    }

    // T partial + per-column sums over this block's 16 rows
    float T = 0.f;
    float cL[6], cQ[6];
#pragma unroll
    for (int ni = 0; ni < 6; ++ni) { cL[ni] = 0.f; cQ[ni] = 0.f; }
#pragma unroll
    for (int r = 0; r < 4; ++r) {
        const float sh  = shx[r];
        const float m   = my_[r];
        const float inv = invy[r];
#pragma unroll
        for (int ni = 0; ni < 6; ++ni) {
            const float lp = accx[ni][r] - sh;
            const float qv = __expf(accy[ni][r] - m) * inv;
            T += lp * qv;
            cL[ni] += lp;
            cQ[ni] += qv;
        }
    }
    // reduce col sums over lq (lanes lm, lm+16, lm+32, lm+48) -> 16 rows
#pragma unroll
    for (int ni = 0; ni < 6; ++ni) {
        cL[ni] += __shfl_xor(cL[ni], 16); cL[ni] += __shfl_xor(cL[ni], 32);
        cQ[ni] += __shfl_xor(cQ[ni], 16); cQ[ni] += __shfl_xor(cQ[ni], 32);
    }
    if (lq == 0)
#pragma unroll
        for (int ni = 0; ni < 6; ++ni) {
            Lg[(size_t)blk * HID + wave * 96 + ni * 16 + lm] = cL[ni];
            Qg[(size_t)blk * HID + wave * 96 + ni * 16 + lm] = cQ[ni];
        }
    // wave-reduce T, then block sum -> global atomic
#pragma unroll
    for (int off = 32; off > 0; off >>= 1) T += __shfl_xor(T, off);
    if (lane == 0) sT[wave] = T;
    __syncthreads();
    if (tid == 0) atomicAdd(&scal[0], sT[0] + sT[1] + sT[2] + sT[3]);
}

// ---------------- finish: S = sum_p sum_c L_p[c]*Q_p[c], final scalar -------
// grid 196 (one block per position), block 384 = 6 waves.
__global__ __launch_bounds__(384) void finish(const float* __restrict__ Lg,
                                              const float* __restrict__ Qg,
                                              float* __restrict__ scal,
                                              float* __restrict__ out) {
    const int p = blockIdx.x;
    const int c = threadIdx.x;                 // 0..383
    const size_t b0 = (size_t)(p * 4) * HID + c;
    const float L = Lg[b0] + Lg[b0 + HID] + Lg[b0 + 2 * HID] + Lg[b0 + 3 * HID];
    const float Q = Qg[b0] + Qg[b0 + HID] + Qg[b0 + 2 * HID] + Qg[b0 + 3 * HID];
    float s = L * Q;
#pragma unroll
    for (int off = 32; off > 0; off >>= 1) s += __shfl_xor(s, off);
    __shared__ float sw[6];
    if ((c & 63) == 0) sw[c >> 6] = s;
    __syncthreads();
    if (c == 0) {
        const float Sp = sw[0] + sw[1] + sw[2] + sw[3] + sw[4] + sw[5];
        atomicAdd(&scal[1], Sp);
        __threadfence();
        const int old = atomicAdd((int*)&scal[3], 1);
        if (old == 195) {
            const float T = atomicAdd(&scal[0], 0.f);   // coherent read-back
            const float S = atomicAdd(&scal[1], 0.f);
            out[0] = 63.f * T / (S - T);
        }
    }
}

extern "C" void kernel_launch(void* const* d_in, const int* in_sizes, int n_in,
                              void* d_out, int out_size, void* d_ws, size_t ws_size,
                              hipStream_t stream) {
    const float* x = (const float*)d_in[0];   // (64,3,224,224)
    const float* y = (const float*)d_in[1];   // (64,3,224,224)
    const float* W = (const float*)d_in[2];   // (384,768)
    const float* b = (const float*)d_in[3];   // (384,)
    float* out = (float*)d_out;

    float*    scal  = (float*)d_ws;                       // 16 f32: T,S,pad,cnt
    ushort_t* Wfrag = (ushort_t*)(scal + 16);             // 294912 bf16 (576 KB)
    float*    Lg    = (float*)(Wfrag + 294912);           // 784 x 384 f32
    float*    Qg    = Lg + (size_t)784 * HID;             // 784 x 384 f32

    prep<<<144, 256, 0, stream>>>(W, Wfrag, scal);
    pe_all<<<784, 256, 0, stream>>>(x, y, Wfrag, b, scal, Lg, Qg);
    finish<<<196, 384, 0, stream>>>(Lg, Qg, scal, out);
}